// Round 1
// baseline (6648.856 us; speedup 1.0000x reference)
//
#include <hip/hip_runtime.h>

#define N_NODES 100000
#define N_EDGES 1600000
#define D_IN 128
#define D_HID 128
#define D_LAT 64

// ---------------- degree: deg[dst] += 1 ----------------
__global__ void deg_kernel(const int* __restrict__ dst, float* __restrict__ deg) {
    int e = blockIdx.x * blockDim.x + threadIdx.x;
    if (e < N_EDGES) atomicAdd(&deg[dst[e]], 1.0f);
}

// ---------------- scatter-add: agg[dst,:] += feat[src,:] ----------------
// D = 128 features, 32 lanes per edge, float4 per lane, 8 edges / 256-thread block
__global__ void scatter128_kernel(const int* __restrict__ src, const int* __restrict__ dst,
                                  const float* __restrict__ feat, float* __restrict__ agg) {
    int lane   = threadIdx.x & 31;
    int eLocal = threadIdx.x >> 5;
    long e = (long)blockIdx.x * 8 + eLocal;
    if (e >= N_EDGES) return;
    int s = src[e];
    int d = dst[e];
    const float4 v = ((const float4*)(feat + (long)s * D_IN))[lane];
    float* a = agg + (long)d * D_IN + lane * 4;
    atomicAdd(a + 0, v.x);
    atomicAdd(a + 1, v.y);
    atomicAdd(a + 2, v.z);
    atomicAdd(a + 3, v.w);
}

// ---------------- fused SAGE MLP ----------------
// out[i,j] = relu( (agg[i,:]*inv_deg) @ Wl[:,j] + b[j] + xin[i,:] @ Wr[:,j] )
// blockDim.x = N (output cols), blockDim.y rows per block.
template<int K, int N>
__global__ void sage_mlp_kernel(const float* __restrict__ agg, const float* __restrict__ deg,
                                const float* __restrict__ xin,
                                const float* __restrict__ Wl, const float* __restrict__ Wr,
                                const float* __restrict__ b, float* __restrict__ out) {
    int j = threadIdx.x;
    long i = (long)blockIdx.x * blockDim.y + threadIdx.y;
    if (i >= N_NODES) return;
    float inv = 1.0f / fmaxf(deg[i], 1.0f);
    float acc = b[j];
    const float4* ar = (const float4*)(agg + i * K);
    const float4* xr = (const float4*)(xin + i * K);
    #pragma unroll
    for (int k4 = 0; k4 < K / 4; ++k4) {
        float4 a4 = ar[k4];
        float4 x4 = xr[k4];
        int k = k4 * 4;
        acc = fmaf(a4.x * inv, Wl[(k + 0) * N + j], acc);
        acc = fmaf(x4.x,       Wr[(k + 0) * N + j], acc);
        acc = fmaf(a4.y * inv, Wl[(k + 1) * N + j], acc);
        acc = fmaf(x4.y,       Wr[(k + 1) * N + j], acc);
        acc = fmaf(a4.z * inv, Wl[(k + 2) * N + j], acc);
        acc = fmaf(x4.z,       Wr[(k + 2) * N + j], acc);
        acc = fmaf(a4.w * inv, Wl[(k + 3) * N + j], acc);
        acc = fmaf(x4.w,       Wr[(k + 3) * N + j], acc);
    }
    out[i * N + j] = fmaxf(acc, 0.0f);
}

extern "C" void kernel_launch(void* const* d_in, const int* in_sizes, int n_in,
                              void* d_out, int out_size, void* d_ws, size_t ws_size,
                              hipStream_t stream) {
    const float* x    = (const float*)d_in[0];
    const int*   ei   = (const int*)d_in[1];     // [2, N_EDGES] int32 (JAX x64-off canonicalization)
    const float* W1_l = (const float*)d_in[2];
    const float* W1_r = (const float*)d_in[3];
    const float* b1   = (const float*)d_in[4];
    const float* W2_l = (const float*)d_in[5];
    const float* W2_r = (const float*)d_in[6];
    const float* b2   = (const float*)d_in[7];
    float* out = (float*)d_out;

    const int* src = ei;
    const int* dst = ei + N_EDGES;

    // workspace layout (floats): deg [0, 100000), agg at 131072 (512KB byte offset),
    // h after agg. agg/h are N_NODES*128 floats each.
    float* wsf = (float*)d_ws;
    float* deg = wsf;
    float* agg = wsf + 131072;
    float* h   = agg + (long)N_NODES * D_HID;

    const size_t zero1_bytes = 131072 * sizeof(float) + (size_t)N_NODES * D_HID * sizeof(float);
    const size_t agg_bytes   = (size_t)N_NODES * D_HID * sizeof(float);

    // ---- layer 1 ----
    hipMemsetAsync(d_ws, 0, zero1_bytes, stream);                       // deg + agg = 0
    deg_kernel<<<(N_EDGES + 255) / 256, 256, 0, stream>>>(dst, deg);
    scatter128_kernel<<<(N_EDGES + 7) / 8, 256, 0, stream>>>(src, dst, x, agg);
    {
        dim3 blk(D_HID, 4);
        int grid = (N_NODES + 3) / 4;
        sage_mlp_kernel<D_IN, D_HID><<<grid, blk, 0, stream>>>(agg, deg, x, W1_l, W1_r, b1, h);
    }

    // ---- layer 2 ----
    hipMemsetAsync(agg, 0, agg_bytes, stream);
    scatter128_kernel<<<(N_EDGES + 7) / 8, 256, 0, stream>>>(src, dst, h, agg);
    {
        dim3 blk(D_LAT, 8);
        int grid = (N_NODES + 7) / 8;
        sage_mlp_kernel<D_HID, D_LAT><<<grid, blk, 0, stream>>>(agg, deg, h, W2_l, W2_r, b2, out);
    }
}

// Round 2
// 1821.204 us; speedup vs baseline: 3.6508x; 3.6508x over previous
//
#include <hip/hip_runtime.h>

#define N_NODES 100000
#define N_EDGES 1600000
#define D_IN 128
#define D_HID 128
#define D_LAT 64

// ---------------- CSR build step 1: degree histogram (int atomics) ----------------
__global__ void hist_kernel(const int* __restrict__ dst, int* __restrict__ deg) {
    int e = blockIdx.x * blockDim.x + threadIdx.x;
    if (e < N_EDGES) atomicAdd(&deg[dst[e]], 1);
}

// ---------------- CSR build step 2: exclusive scan (single block, 1024 threads) ----
// off[i] = sum_{k<i} deg[k]; cursor[i] = off[i]; off[N_NODES] = total.
__global__ void scan_kernel(const int* __restrict__ deg, int* __restrict__ off,
                            int* __restrict__ cursor) {
    __shared__ int partials[1024];
    const int CHUNK = (N_NODES + 1023) / 1024;  // 98
    int t = threadIdx.x;
    int base = t * CHUNK;
    int s = 0;
    for (int k = 0; k < CHUNK; ++k) {
        int idx = base + k;
        if (idx < N_NODES) s += deg[idx];
    }
    partials[t] = s;
    __syncthreads();
    // naive inclusive scan over 1024 partials
    for (int d = 1; d < 1024; d <<= 1) {
        int v = (t >= d) ? partials[t - d] : 0;
        __syncthreads();
        partials[t] += v;
        __syncthreads();
    }
    int ex = (t == 0) ? 0 : partials[t - 1];
    for (int k = 0; k < CHUNK; ++k) {
        int idx = base + k;
        if (idx < N_NODES) {
            off[idx] = ex;
            cursor[idx] = ex;
            ex += deg[idx];
        }
    }
    if (t == 1023) off[N_NODES] = ex;  // == total edges
}

// ---------------- CSR build step 3: scatter edge ids into slots ----------------
__global__ void fill_csr_kernel(const int* __restrict__ src, const int* __restrict__ dst,
                                int* __restrict__ cursor, int* __restrict__ csr_src) {
    int e = blockIdx.x * blockDim.x + threadIdx.x;
    if (e < N_EDGES) {
        int p = atomicAdd(&cursor[dst[e]], 1);
        csr_src[p] = src[e];
    }
}

// ---------------- gather-mean: mean[i,:] = sum_{k in row i} feat[csr_src[k],:] / deg ----
// 32 lanes per node (float4 each -> 128 floats), 8 nodes per 256-thread block.
template<int D>
__global__ void gather_mean_kernel(const int* __restrict__ off, const int* __restrict__ csr_src,
                                   const float* __restrict__ feat, float* __restrict__ mean_out) {
    int lane = threadIdx.x & 31;
    int local = threadIdx.x >> 5;
    long i = (long)blockIdx.x * 8 + local;
    if (i >= N_NODES) return;
    int beg = off[i], end = off[i + 1];
    float4 acc = make_float4(0.f, 0.f, 0.f, 0.f);
    for (int k = beg; k < end; ++k) {
        int s = csr_src[k];
        float4 v = ((const float4*)(feat + (long)s * D))[lane];
        acc.x += v.x; acc.y += v.y; acc.z += v.z; acc.w += v.w;
    }
    float inv = (end > beg) ? 1.0f / (float)(end - beg) : 0.0f;
    acc.x *= inv; acc.y *= inv; acc.z *= inv; acc.w *= inv;
    ((float4*)(mean_out + i * D))[lane] = acc;
}

// ---------------- fused SAGE MLP ----------------
// out[i,j] = relu( mean[i,:] @ Wl[:,j] + b[j] + xin[i,:] @ Wr[:,j] )
template<int K, int N>
__global__ void sage_mlp_kernel(const float* __restrict__ mean, const float* __restrict__ xin,
                                const float* __restrict__ Wl, const float* __restrict__ Wr,
                                const float* __restrict__ b, float* __restrict__ out) {
    int j = threadIdx.x;
    long i = (long)blockIdx.x * blockDim.y + threadIdx.y;
    if (i >= N_NODES) return;
    float acc = b[j];
    const float4* ar = (const float4*)(mean + i * K);
    const float4* xr = (const float4*)(xin + i * K);
    #pragma unroll
    for (int k4 = 0; k4 < K / 4; ++k4) {
        float4 a4 = ar[k4];
        float4 x4 = xr[k4];
        int k = k4 * 4;
        acc = fmaf(a4.x, Wl[(k + 0) * N + j], acc);
        acc = fmaf(x4.x, Wr[(k + 0) * N + j], acc);
        acc = fmaf(a4.y, Wl[(k + 1) * N + j], acc);
        acc = fmaf(x4.y, Wr[(k + 1) * N + j], acc);
        acc = fmaf(a4.z, Wl[(k + 2) * N + j], acc);
        acc = fmaf(x4.z, Wr[(k + 2) * N + j], acc);
        acc = fmaf(a4.w, Wl[(k + 3) * N + j], acc);
        acc = fmaf(x4.w, Wr[(k + 3) * N + j], acc);
    }
    out[i * N + j] = fmaxf(acc, 0.0f);
}

extern "C" void kernel_launch(void* const* d_in, const int* in_sizes, int n_in,
                              void* d_out, int out_size, void* d_ws, size_t ws_size,
                              hipStream_t stream) {
    const float* x    = (const float*)d_in[0];
    const int*   ei   = (const int*)d_in[1];     // [2, N_EDGES] int32
    const float* W1_l = (const float*)d_in[2];
    const float* W1_r = (const float*)d_in[3];
    const float* b1   = (const float*)d_in[4];
    const float* W2_l = (const float*)d_in[5];
    const float* W2_r = (const float*)d_in[6];
    const float* b2   = (const float*)d_in[7];
    float* out = (float*)d_out;

    const int* src = ei;
    const int* dst = ei + N_EDGES;

    // workspace layout
    int* deg_i  = (int*)d_ws;                   // 100352 ints (padded)
    int* off    = deg_i + 100352;               // 100352 ints (needs 100001)
    int* cursor = off + 100352;                 // 100352 ints
    int* csr    = cursor + 100352;              // 1.6M ints
    float* mean = (float*)(csr + N_EDGES);      // N_NODES*128 floats (51.2 MB), 16B-aligned
    float* h    = mean + (long)N_NODES * D_HID; // N_NODES*128 floats (51.2 MB)

    // ---- CSR build (once; reused by both layers) ----
    hipMemsetAsync(deg_i, 0, 100352 * sizeof(int), stream);
    hist_kernel<<<(N_EDGES + 255) / 256, 256, 0, stream>>>(dst, deg_i);
    scan_kernel<<<1, 1024, 0, stream>>>(deg_i, off, cursor);
    fill_csr_kernel<<<(N_EDGES + 255) / 256, 256, 0, stream>>>(src, dst, cursor, csr);

    // ---- layer 1 ----
    gather_mean_kernel<D_IN><<<(N_NODES + 7) / 8, 256, 0, stream>>>(off, csr, x, mean);
    {
        dim3 blk(D_HID, 4);
        sage_mlp_kernel<D_IN, D_HID><<<(N_NODES + 3) / 4, blk, 0, stream>>>(mean, x, W1_l, W1_r, b1, h);
    }

    // ---- layer 2 ----
    gather_mean_kernel<D_HID><<<(N_NODES + 7) / 8, 256, 0, stream>>>(off, csr, h, mean);
    {
        dim3 blk(D_LAT, 8);
        sage_mlp_kernel<D_HID, D_LAT><<<(N_NODES + 7) / 8, blk, 0, stream>>>(mean, h, W2_l, W2_r, b2, out);
    }
}

// Round 3
// 731.741 us; speedup vs baseline: 9.0864x; 2.4889x over previous
//
#include <hip/hip_runtime.h>

#define N_NODES 100000
#define N_EDGES 1600000
#define D_IN 128
#define D_HID 128
#define D_LAT 64

typedef unsigned short ushort_t;
typedef unsigned int uint_t;
using bf16x8 = __attribute__((ext_vector_type(8))) short;
using f32x4  = __attribute__((ext_vector_type(4))) float;

__device__ inline ushort_t f2bf(float f) {
    uint_t u = __float_as_uint(f);
    return (ushort_t)((u + 0x7fffu + ((u >> 16) & 1u)) >> 16);   // RNE
}
__device__ inline uint_t pack2bf(float a, float b) {
    return (uint_t)f2bf(a) | ((uint_t)f2bf(b) << 16);
}

// ---------------- CSR build ----------------
__global__ void hist_kernel(const int* __restrict__ dst, int* __restrict__ deg) {
    int e = blockIdx.x * blockDim.x + threadIdx.x;
    if (e < N_EDGES) atomicAdd(&deg[dst[e]], 1);
}

__global__ void scan_kernel(const int* __restrict__ deg, int* __restrict__ off,
                            int* __restrict__ cursor) {
    __shared__ int partials[1024];
    const int CHUNK = (N_NODES + 1023) / 1024;
    int t = threadIdx.x;
    int base = t * CHUNK;
    int s = 0;
    for (int k = 0; k < CHUNK; ++k) {
        int idx = base + k;
        if (idx < N_NODES) s += deg[idx];
    }
    partials[t] = s;
    __syncthreads();
    for (int d = 1; d < 1024; d <<= 1) {
        int v = (t >= d) ? partials[t - d] : 0;
        __syncthreads();
        partials[t] += v;
        __syncthreads();
    }
    int ex = (t == 0) ? 0 : partials[t - 1];
    for (int k = 0; k < CHUNK; ++k) {
        int idx = base + k;
        if (idx < N_NODES) {
            off[idx] = ex;
            cursor[idx] = ex;
            ex += deg[idx];
        }
    }
    if (t == 1023) off[N_NODES] = ex;
}

__global__ void fill_csr_kernel(const int* __restrict__ src, const int* __restrict__ dst,
                                int* __restrict__ cursor, int* __restrict__ csr_src) {
    int e = blockIdx.x * blockDim.x + threadIdx.x;
    if (e < N_EDGES) {
        int p = atomicAdd(&cursor[dst[e]], 1);
        csr_src[p] = src[e];
    }
}

// ---------------- fp32 -> bf16 conversion (8 elems/thread) ----------------
__global__ void cvt_bf16_kernel(const float* __restrict__ in, ushort_t* __restrict__ out, long n) {
    long i = ((long)blockIdx.x * blockDim.x + threadIdx.x) * 8;
    if (i >= n) return;
    float4 a = *(const float4*)(in + i);
    float4 b = *(const float4*)(in + i + 4);
    uint4 o;
    o.x = pack2bf(a.x, a.y);
    o.y = pack2bf(a.z, a.w);
    o.z = pack2bf(b.x, b.y);
    o.w = pack2bf(b.z, b.w);
    *(uint4*)(out + i) = o;
}

// ---------------- pack [Wl;Wr] (K=256 x N) into MFMA B-fragment order ----------------
// dest: [N/16][K/32][64 lanes][8 bf16]; lane holds B[k=kt*32+quad*8+j][n=nt*16+(lane&15)]
__global__ void pack_w_kernel(const float* __restrict__ Wl, const float* __restrict__ Wr,
                              ushort_t* __restrict__ pack, int N) {
    int tid = blockIdx.x * blockDim.x + threadIdx.x;
    int total = (N / 16) * 8 * 64;
    if (tid >= total) return;
    int lane = tid & 63;
    int t = tid >> 6;
    int kt = t & 7;
    int nt = t >> 3;
    int n = nt * 16 + (lane & 15);
    int kbase = kt * 32 + (lane >> 4) * 8;
    ushort_t v[8];
    #pragma unroll
    for (int j = 0; j < 8; ++j) {
        int k = kbase + j;
        float w = (k < 128) ? Wl[k * N + n] : Wr[(k - 128) * N + n];
        v[j] = f2bf(w);
    }
    *(uint4*)(pack + (long)tid * 8) = *(uint4*)v;
}

// ---------------- gather-mean (bf16 in, fp32 acc, bf16 out) ----------------
// 16 lanes per node (16B each), 16 nodes per 256-thread block. D fixed = 128.
__global__ void gather_mean_kernel(const int* __restrict__ off, const int* __restrict__ csr_src,
                                   const ushort_t* __restrict__ feat, ushort_t* __restrict__ mean_out) {
    int lane  = threadIdx.x & 15;
    int local = threadIdx.x >> 4;
    long i = (long)blockIdx.x * 16 + local;
    if (i >= N_NODES) return;
    int beg = off[i], end = off[i + 1];
    float acc[8] = {0.f, 0.f, 0.f, 0.f, 0.f, 0.f, 0.f, 0.f};
    for (int k = beg; k < end; ++k) {
        int s = csr_src[k];
        uint4 u = *(const uint4*)(feat + (long)s * 128 + lane * 8);
        acc[0] += __uint_as_float(u.x << 16);
        acc[1] += __uint_as_float(u.x & 0xffff0000u);
        acc[2] += __uint_as_float(u.y << 16);
        acc[3] += __uint_as_float(u.y & 0xffff0000u);
        acc[4] += __uint_as_float(u.z << 16);
        acc[5] += __uint_as_float(u.z & 0xffff0000u);
        acc[6] += __uint_as_float(u.w << 16);
        acc[7] += __uint_as_float(u.w & 0xffff0000u);
    }
    float inv = (end > beg) ? 1.f / (float)(end - beg) : 0.f;
    uint4 o;
    o.x = pack2bf(acc[0] * inv, acc[1] * inv);
    o.y = pack2bf(acc[2] * inv, acc[3] * inv);
    o.z = pack2bf(acc[4] * inv, acc[5] * inv);
    o.w = pack2bf(acc[6] * inv, acc[7] * inv);
    *(uint4*)(mean_out + i * 128 + lane * 8) = o;
}

// ---------------- MFMA MLP: out = relu([mean|x] @ packedW + b) ----------------
// M=100000, K=256. Block = 4 waves, each wave does 16 rows x NOUT cols.
template<int NOUT, bool OUT_BF16>
__global__ __launch_bounds__(256) void mfma_mlp_kernel(
        const ushort_t* __restrict__ Am, const ushort_t* __restrict__ Ax,
        const ushort_t* __restrict__ pack, const float* __restrict__ bias,
        void* __restrict__ outv) {
    constexpr int NT = NOUT / 16;
    int lane = threadIdx.x & 63;
    int wave = threadIdx.x >> 6;
    long m0 = (long)blockIdx.x * 64 + wave * 16;
    int r = lane & 15;          // A row within tile; C/D column within tile
    int quad = lane >> 4;
    long arow = m0 + r;
    if (arow > N_NODES - 1) arow = N_NODES - 1;   // clamp loads; stores guarded

    bf16x8 areg[8];
    #pragma unroll
    for (int kt = 0; kt < 8; ++kt) {
        const ushort_t* s = (kt < 4) ? Am : Ax;
        int k = (kt & 3) * 32 + quad * 8;
        areg[kt] = *(const bf16x8*)(s + arow * 128 + k);
    }

    f32x4 acc[NT];
    #pragma unroll
    for (int nt = 0; nt < NT; ++nt) acc[nt] = (f32x4){0.f, 0.f, 0.f, 0.f};

    #pragma unroll
    for (int nt = 0; nt < NT; ++nt) {
        #pragma unroll
        for (int kt = 0; kt < 8; ++kt) {
            bf16x8 bfrag = *(const bf16x8*)(pack + ((long)(nt * 8 + kt) * 64 + lane) * 8);
            acc[nt] = __builtin_amdgcn_mfma_f32_16x16x32_bf16(areg[kt], bfrag, acc[nt], 0, 0, 0);
        }
    }

    #pragma unroll
    for (int nt = 0; nt < NT; ++nt) {
        int col = nt * 16 + r;
        float bj = bias[col];
        #pragma unroll
        for (int q = 0; q < 4; ++q) {
            long orow = m0 + quad * 4 + q;
            if (orow < N_NODES) {
                float v = fmaxf(acc[nt][q] + bj, 0.f);
                if (OUT_BF16) ((ushort_t*)outv)[orow * NOUT + col] = f2bf(v);
                else          ((float*)outv)[orow * NOUT + col] = v;
            }
        }
    }
}

extern "C" void kernel_launch(void* const* d_in, const int* in_sizes, int n_in,
                              void* d_out, int out_size, void* d_ws, size_t ws_size,
                              hipStream_t stream) {
    const float* x    = (const float*)d_in[0];
    const int*   ei   = (const int*)d_in[1];
    const float* W1_l = (const float*)d_in[2];
    const float* W1_r = (const float*)d_in[3];
    const float* b1   = (const float*)d_in[4];
    const float* W2_l = (const float*)d_in[5];
    const float* W2_r = (const float*)d_in[6];
    const float* b2   = (const float*)d_in[7];
    float* out = (float*)d_out;

    const int* src = ei;
    const int* dst = ei + N_EDGES;

    // workspace layout (all 16B aligned)
    int* deg_i  = (int*)d_ws;                      // 100352
    int* off    = deg_i + 100352;                  // 100352
    int* cursor = off + 100352;                    // 100352
    int* csr    = cursor + 100352;                 // 1.6M
    ushort_t* xb    = (ushort_t*)(csr + N_EDGES);  // 100000*128 bf16 (25.6 MB)
    ushort_t* meanb = xb + (long)N_NODES * 128;    // 25.6 MB
    ushort_t* hb    = meanb + (long)N_NODES * 128; // 25.6 MB
    ushort_t* pack1 = hb + (long)N_NODES * 128;    // 256*128 bf16
    ushort_t* pack2 = pack1 + 256 * 128;           // 256*64 bf16

    // ---- CSR build ----
    hipMemsetAsync(deg_i, 0, 100352 * sizeof(int), stream);
    hist_kernel<<<(N_EDGES + 255) / 256, 256, 0, stream>>>(dst, deg_i);
    scan_kernel<<<1, 1024, 0, stream>>>(deg_i, off, cursor);
    fill_csr_kernel<<<(N_EDGES + 255) / 256, 256, 0, stream>>>(src, dst, cursor, csr);

    // ---- precision prep ----
    cvt_bf16_kernel<<<((long)N_NODES * 128 / 8 + 255) / 256, 256, 0, stream>>>(
        x, xb, (long)N_NODES * 128);
    pack_w_kernel<<<((128 / 16) * 8 * 64 + 255) / 256, 256, 0, stream>>>(W1_l, W1_r, pack1, 128);
    pack_w_kernel<<<((64 / 16) * 8 * 64 + 255) / 256, 256, 0, stream>>>(W2_l, W2_r, pack2, 64);

    // ---- layer 1 ----
    gather_mean_kernel<<<(N_NODES + 15) / 16, 256, 0, stream>>>(off, csr, xb, meanb);
    mfma_mlp_kernel<128, true><<<(N_NODES + 63) / 64, 256, 0, stream>>>(meanb, xb, pack1, b1, hb);

    // ---- layer 2 ----
    gather_mean_kernel<<<(N_NODES + 15) / 16, 256, 0, stream>>>(off, csr, hb, meanb);
    mfma_mlp_kernel<64, false><<<(N_NODES + 63) / 64, 256, 0, stream>>>(meanb, hb, pack2, b2, out);
}

// Round 4
// 490.921 us; speedup vs baseline: 13.5436x; 1.4905x over previous
//
#include <hip/hip_runtime.h>

#define N_NODES 100000
#define N_EDGES 1600000
#define D_IN 128
#define D_HID 128
#define D_LAT 64

#define SCAN_BLOCKS 98   // 98 * 1024 = 100352 >= N_NODES (deg zero-padded to 100352)

typedef unsigned short ushort_t;
typedef unsigned int uint_t;
using bf16x8 = __attribute__((ext_vector_type(8))) short;
using f32x4  = __attribute__((ext_vector_type(4))) float;

__device__ inline ushort_t f2bf(float f) {
    uint_t u = __float_as_uint(f);
    return (ushort_t)((u + 0x7fffu + ((u >> 16) & 1u)) >> 16);   // RNE
}
__device__ inline uint_t pack2bf(float a, float b) {
    return (uint_t)f2bf(a) | ((uint_t)f2bf(b) << 16);
}

// ---------------- CSR build ----------------
__global__ void hist_kernel(const int* __restrict__ dst, int* __restrict__ deg) {
    int e = blockIdx.x * blockDim.x + threadIdx.x;
    if (e < N_EDGES) atomicAdd(&deg[dst[e]], 1);
}

// phase 1: per-block (1024 elems) totals
__global__ __launch_bounds__(256) void reduce_deg_kernel(const int* __restrict__ deg,
                                                         int* __restrict__ blockSums) {
    __shared__ int wsum[4];
    int t = threadIdx.x;
    int4 d = *(const int4*)(deg + blockIdx.x * 1024 + t * 4);
    int s = d.x + d.y + d.z + d.w;
    #pragma unroll
    for (int o = 32; o > 0; o >>= 1) s += __shfl_down(s, o, 64);
    if ((t & 63) == 0) wsum[t >> 6] = s;
    __syncthreads();
    if (t == 0) blockSums[blockIdx.x] = wsum[0] + wsum[1] + wsum[2] + wsum[3];
}

// phase 2: each block: prefix of blockSums + local scan + write off/cursor
__global__ __launch_bounds__(256) void scan_write_kernel(const int* __restrict__ deg,
                                                         const int* __restrict__ blockSums,
                                                         int* __restrict__ off,
                                                         int* __restrict__ cursor) {
    __shared__ int sbs[SCAN_BLOCKS];
    __shared__ int sdata[256];
    int t = threadIdx.x;
    int b = blockIdx.x;
    if (t < SCAN_BLOCKS) sbs[t] = blockSums[t];
    int idx = b * 1024 + t * 4;
    int4 d = *(const int4*)(deg + idx);
    int ts = d.x + d.y + d.z + d.w;
    sdata[t] = ts;
    __syncthreads();
    int prefix = 0;
    for (int k = 0; k < SCAN_BLOCKS; ++k) prefix += (k < b) ? sbs[k] : 0;
    // Hillis-Steele inclusive scan over 256 thread sums
    #pragma unroll
    for (int dd = 1; dd < 256; dd <<= 1) {
        int v = (t >= dd) ? sdata[t - dd] : 0;
        __syncthreads();
        sdata[t] += v;
        __syncthreads();
    }
    int ex = prefix + ((t == 0) ? 0 : sdata[t - 1]);
    int4 o;
    o.x = ex;
    o.y = ex + d.x;
    o.z = ex + d.x + d.y;
    o.w = ex + d.x + d.y + d.z;
    *(int4*)(off + idx) = o;
    *(int4*)(cursor + idx) = o;
    // note: deg zero-padded past N_NODES, so off[N_NODES] = total = N_EDGES
    // is written naturally by the block covering idx==N_NODES.
}

__global__ void fill_csr_kernel(const int* __restrict__ src, const int* __restrict__ dst,
                                int* __restrict__ cursor, int* __restrict__ csr_src) {
    int e = blockIdx.x * blockDim.x + threadIdx.x;
    if (e < N_EDGES) {
        int p = atomicAdd(&cursor[dst[e]], 1);
        csr_src[p] = src[e];
    }
}

// ---------------- fp32 -> bf16 conversion (8 elems/thread) ----------------
__global__ void cvt_bf16_kernel(const float* __restrict__ in, ushort_t* __restrict__ out, long n) {
    long i = ((long)blockIdx.x * blockDim.x + threadIdx.x) * 8;
    if (i >= n) return;
    float4 a = *(const float4*)(in + i);
    float4 b = *(const float4*)(in + i + 4);
    uint4 o;
    o.x = pack2bf(a.x, a.y);
    o.y = pack2bf(a.z, a.w);
    o.z = pack2bf(b.x, b.y);
    o.w = pack2bf(b.z, b.w);
    *(uint4*)(out + i) = o;
}

// ---------------- pack [Wl;Wr] (K=256 x N) into MFMA B-fragment order ----------------
__global__ void pack_w_kernel(const float* __restrict__ Wl, const float* __restrict__ Wr,
                              ushort_t* __restrict__ pack, int N) {
    int tid = blockIdx.x * blockDim.x + threadIdx.x;
    int total = (N / 16) * 8 * 64;
    if (tid >= total) return;
    int lane = tid & 63;
    int t = tid >> 6;
    int kt = t & 7;
    int nt = t >> 3;
    int n = nt * 16 + (lane & 15);
    int kbase = kt * 32 + (lane >> 4) * 8;
    ushort_t v[8];
    #pragma unroll
    for (int j = 0; j < 8; ++j) {
        int k = kbase + j;
        float w = (k < 128) ? Wl[k * N + n] : Wr[(k - 128) * N + n];
        v[j] = f2bf(w);
    }
    *(uint4*)(pack + (long)tid * 8) = *(uint4*)v;
}

// ---------------- gather-mean (bf16 in, fp32 acc, bf16 out) ----------------
__global__ void gather_mean_kernel(const int* __restrict__ off, const int* __restrict__ csr_src,
                                   const ushort_t* __restrict__ feat, ushort_t* __restrict__ mean_out) {
    int lane  = threadIdx.x & 15;
    int local = threadIdx.x >> 4;
    long i = (long)blockIdx.x * 16 + local;
    if (i >= N_NODES) return;
    int beg = off[i], end = off[i + 1];
    float acc[8] = {0.f, 0.f, 0.f, 0.f, 0.f, 0.f, 0.f, 0.f};
    for (int k = beg; k < end; ++k) {
        int s = csr_src[k];
        uint4 u = *(const uint4*)(feat + (long)s * 128 + lane * 8);
        acc[0] += __uint_as_float(u.x << 16);
        acc[1] += __uint_as_float(u.x & 0xffff0000u);
        acc[2] += __uint_as_float(u.y << 16);
        acc[3] += __uint_as_float(u.y & 0xffff0000u);
        acc[4] += __uint_as_float(u.z << 16);
        acc[5] += __uint_as_float(u.z & 0xffff0000u);
        acc[6] += __uint_as_float(u.w << 16);
        acc[7] += __uint_as_float(u.w & 0xffff0000u);
    }
    float inv = (end > beg) ? 1.f / (float)(end - beg) : 0.f;
    uint4 o;
    o.x = pack2bf(acc[0] * inv, acc[1] * inv);
    o.y = pack2bf(acc[2] * inv, acc[3] * inv);
    o.z = pack2bf(acc[4] * inv, acc[5] * inv);
    o.w = pack2bf(acc[6] * inv, acc[7] * inv);
    *(uint4*)(mean_out + i * 128 + lane * 8) = o;
}

// ---------------- MFMA MLP: out = relu([mean|x] @ packedW + b) ----------------
template<int NOUT, bool OUT_BF16>
__global__ __launch_bounds__(256) void mfma_mlp_kernel(
        const ushort_t* __restrict__ Am, const ushort_t* __restrict__ Ax,
        const ushort_t* __restrict__ pack, const float* __restrict__ bias,
        void* __restrict__ outv) {
    constexpr int NT = NOUT / 16;
    int lane = threadIdx.x & 63;
    int wave = threadIdx.x >> 6;
    long m0 = (long)blockIdx.x * 64 + wave * 16;
    int r = lane & 15;
    int quad = lane >> 4;
    long arow = m0 + r;
    if (arow > N_NODES - 1) arow = N_NODES - 1;

    bf16x8 areg[8];
    #pragma unroll
    for (int kt = 0; kt < 8; ++kt) {
        const ushort_t* s = (kt < 4) ? Am : Ax;
        int k = (kt & 3) * 32 + quad * 8;
        areg[kt] = *(const bf16x8*)(s + arow * 128 + k);
    }

    f32x4 acc[NT];
    #pragma unroll
    for (int nt = 0; nt < NT; ++nt) acc[nt] = (f32x4){0.f, 0.f, 0.f, 0.f};

    #pragma unroll
    for (int nt = 0; nt < NT; ++nt) {
        #pragma unroll
        for (int kt = 0; kt < 8; ++kt) {
            bf16x8 bfrag = *(const bf16x8*)(pack + ((long)(nt * 8 + kt) * 64 + lane) * 8);
            acc[nt] = __builtin_amdgcn_mfma_f32_16x16x32_bf16(areg[kt], bfrag, acc[nt], 0, 0, 0);
        }
    }

    #pragma unroll
    for (int nt = 0; nt < NT; ++nt) {
        int col = nt * 16 + r;
        float bj = bias[col];
        #pragma unroll
        for (int q = 0; q < 4; ++q) {
            long orow = m0 + quad * 4 + q;
            if (orow < N_NODES) {
                float v = fmaxf(acc[nt][q] + bj, 0.f);
                if (OUT_BF16) ((ushort_t*)outv)[orow * NOUT + col] = f2bf(v);
                else          ((float*)outv)[orow * NOUT + col] = v;
            }
        }
    }
}

extern "C" void kernel_launch(void* const* d_in, const int* in_sizes, int n_in,
                              void* d_out, int out_size, void* d_ws, size_t ws_size,
                              hipStream_t stream) {
    const float* x    = (const float*)d_in[0];
    const int*   ei   = (const int*)d_in[1];
    const float* W1_l = (const float*)d_in[2];
    const float* W1_r = (const float*)d_in[3];
    const float* b1   = (const float*)d_in[4];
    const float* W2_l = (const float*)d_in[5];
    const float* W2_r = (const float*)d_in[6];
    const float* b2   = (const float*)d_in[7];
    float* out = (float*)d_out;

    const int* src = ei;
    const int* dst = ei + N_EDGES;

    // workspace layout (all 16B aligned)
    int* deg_i  = (int*)d_ws;                      // 100352
    int* off    = deg_i + 100352;                  // 100352
    int* cursor = off + 100352;                    // 100352
    int* bsums  = cursor + 100352;                 // 128 (SCAN_BLOCKS)
    int* csr    = bsums + 128;                     // 1.6M
    ushort_t* xb    = (ushort_t*)(csr + N_EDGES);  // 25.6 MB
    ushort_t* meanb = xb + (long)N_NODES * 128;    // 25.6 MB
    ushort_t* hb    = meanb + (long)N_NODES * 128; // 25.6 MB
    ushort_t* pack1 = hb + (long)N_NODES * 128;    // 256*128 bf16
    ushort_t* pack2 = pack1 + 256 * 128;           // 256*64 bf16

    // ---- CSR build ----
    hipMemsetAsync(deg_i, 0, 100352 * sizeof(int), stream);
    hist_kernel<<<(N_EDGES + 255) / 256, 256, 0, stream>>>(dst, deg_i);
    reduce_deg_kernel<<<SCAN_BLOCKS, 256, 0, stream>>>(deg_i, bsums);
    scan_write_kernel<<<SCAN_BLOCKS, 256, 0, stream>>>(deg_i, bsums, off, cursor);
    fill_csr_kernel<<<(N_EDGES + 255) / 256, 256, 0, stream>>>(src, dst, cursor, csr);

    // ---- precision prep ----
    cvt_bf16_kernel<<<((long)N_NODES * 128 / 8 + 255) / 256, 256, 0, stream>>>(
        x, xb, (long)N_NODES * 128);
    pack_w_kernel<<<((128 / 16) * 8 * 64 + 255) / 256, 256, 0, stream>>>(W1_l, W1_r, pack1, 128);
    pack_w_kernel<<<((64 / 16) * 8 * 64 + 255) / 256, 256, 0, stream>>>(W2_l, W2_r, pack2, 64);

    // ---- layer 1 ----
    gather_mean_kernel<<<(N_NODES + 15) / 16, 256, 0, stream>>>(off, csr, xb, meanb);
    mfma_mlp_kernel<128, true><<<(N_NODES + 63) / 64, 256, 0, stream>>>(meanb, xb, pack1, b1, hb);

    // ---- layer 2 ----
    gather_mean_kernel<<<(N_NODES + 15) / 16, 256, 0, stream>>>(off, csr, hb, meanb);
    mfma_mlp_kernel<64, false><<<(N_NODES + 63) / 64, 256, 0, stream>>>(meanb, hb, pack2, b2, out);
}

// Round 5
// 358.001 us; speedup vs baseline: 18.5722x; 1.3713x over previous
//
#include <hip/hip_runtime.h>

#define N_NODES 100000
#define N_EDGES 1600000
#define D_IN 128
#define D_HID 128
#define D_LAT 64

#define BSHIFT 8                          // 256 nodes per bucket
#define NB 392                            // ceil(100352 / 256) buckets
#define EPB 4096                          // edges per partition block
#define PART_BLOCKS ((N_EDGES + EPB - 1) / EPB)   // 391

typedef unsigned short ushort_t;
typedef unsigned int uint_t;
using bf16x8 = __attribute__((ext_vector_type(8))) short;
using f32x4  = __attribute__((ext_vector_type(4))) float;

__device__ inline ushort_t f2bf(float f) {
    uint_t u = __float_as_uint(f);
    return (ushort_t)((u + 0x7fffu + ((u >> 16) & 1u)) >> 16);   // RNE
}
__device__ inline uint_t pack2bf(float a, float b) {
    return (uint_t)f2bf(a) | ((uint_t)f2bf(b) << 16);
}

// ---------------- CSR build via bucketed counting sort ----------------
// A1: global bucket histogram (LDS-staged)
__global__ __launch_bounds__(256) void bucket_hist_kernel(const int* __restrict__ dst,
                                                          int* __restrict__ gHist) {
    __shared__ int h[NB];
    for (int j = threadIdx.x; j < NB; j += 256) h[j] = 0;
    __syncthreads();
    long base = (long)blockIdx.x * EPB;
    #pragma unroll
    for (int i = 0; i < EPB / 256; ++i) {
        long e = base + i * 256 + threadIdx.x;
        if (e < N_EDGES) atomicAdd(&h[dst[e] >> BSHIFT], 1);
    }
    __syncthreads();
    for (int j = threadIdx.x; j < NB; j += 256)
        if (h[j]) atomicAdd(&gHist[j], h[j]);
}

// scan bucket counts -> bucketBase[NB+1]; init gCursor = base
__global__ __launch_bounds__(512) void bucket_scan_kernel(const int* __restrict__ gHist,
                                                          int* __restrict__ bucketBase,
                                                          int* __restrict__ gCursor) {
    __shared__ int s[512];
    int t = threadIdx.x;
    s[t] = (t < NB) ? gHist[t] : 0;
    __syncthreads();
    for (int d = 1; d < 512; d <<= 1) {
        int u = (t >= d) ? s[t - d] : 0;
        __syncthreads();
        s[t] += u;
        __syncthreads();
    }
    int ex = (t == 0) ? 0 : s[t - 1];
    if (t < NB) { bucketBase[t] = ex; gCursor[t] = ex; }
    if (t == NB) bucketBase[NB] = ex;   // total = N_EDGES
}

// A2: partition edges into bucket regions, packed (dstLocal<<24)|src  (src < 2^24)
__global__ __launch_bounds__(256) void bucket_scatter_kernel(const int* __restrict__ src,
                                                             const int* __restrict__ dst,
                                                             int* __restrict__ gCursor,
                                                             int* __restrict__ bedges) {
    __shared__ int h[NB];
    __shared__ int start[NB];
    for (int j = threadIdx.x; j < NB; j += 256) h[j] = 0;
    __syncthreads();
    long base = (long)blockIdx.x * EPB;
    #pragma unroll
    for (int i = 0; i < EPB / 256; ++i) {
        long e = base + i * 256 + threadIdx.x;
        if (e < N_EDGES) atomicAdd(&h[dst[e] >> BSHIFT], 1);
    }
    __syncthreads();
    for (int j = threadIdx.x; j < NB; j += 256)
        start[j] = h[j] ? atomicAdd(&gCursor[j], h[j]) : 0;
    __syncthreads();
    #pragma unroll
    for (int i = 0; i < EPB / 256; ++i) {
        long e = base + i * 256 + threadIdx.x;
        if (e < N_EDGES) {
            int d = dst[e];
            int b = d >> BSHIFT;
            int p = atomicAdd(&start[b], 1);   // LDS cursor from reserved base
            bedges[p] = ((d & 255) << 24) | src[e];
        }
    }
}

// B: per-bucket LDS counting sort -> csr (contiguous region write) + off
__global__ __launch_bounds__(256) void bucket_sort_kernel(const int* __restrict__ bucketBase,
                                                          const int* __restrict__ bedges,
                                                          int* __restrict__ csr,
                                                          int* __restrict__ off) {
    __shared__ int sdata[256];
    __shared__ int cur[256];
    int b = blockIdx.x, t = threadIdx.x;
    int r0 = bucketBase[b], r1 = bucketBase[b + 1];
    int n = r1 - r0;
    cur[t] = 0;
    __syncthreads();
    for (int k = t; k < n; k += 256) atomicAdd(&cur[(unsigned)bedges[r0 + k] >> 24], 1);
    __syncthreads();
    sdata[t] = cur[t];
    __syncthreads();
    for (int d = 1; d < 256; d <<= 1) {
        int u = (t >= d) ? sdata[t - d] : 0;
        __syncthreads();
        sdata[t] += u;
        __syncthreads();
    }
    int ex = (t == 0) ? 0 : sdata[t - 1];
    off[(b << BSHIFT) + t] = r0 + ex;     // covers nodes 0..100351 (zero-deg pads included)
    cur[t] = ex;
    __syncthreads();
    for (int k = t; k < n; k += 256) {
        int v = bedges[r0 + k];
        int p = atomicAdd(&cur[(unsigned)v >> 24], 1);
        csr[r0 + p] = v & 0xFFFFFF;
    }
}

// ---------------- fp32 -> bf16 conversion (8 elems/thread) ----------------
__global__ void cvt_bf16_kernel(const float* __restrict__ in, ushort_t* __restrict__ out, long n) {
    long i = ((long)blockIdx.x * blockDim.x + threadIdx.x) * 8;
    if (i >= n) return;
    float4 a = *(const float4*)(in + i);
    float4 b = *(const float4*)(in + i + 4);
    uint4 o;
    o.x = pack2bf(a.x, a.y);
    o.y = pack2bf(a.z, a.w);
    o.z = pack2bf(b.x, b.y);
    o.w = pack2bf(b.z, b.w);
    *(uint4*)(out + i) = o;
}

// ---------------- pack [Wl;Wr] (K=256 x N) into MFMA B-fragment order ----------------
__global__ void pack_w_kernel(const float* __restrict__ Wl, const float* __restrict__ Wr,
                              ushort_t* __restrict__ pack, int N) {
    int tid = blockIdx.x * blockDim.x + threadIdx.x;
    int total = (N / 16) * 8 * 64;
    if (tid >= total) return;
    int lane = tid & 63;
    int t = tid >> 6;
    int kt = t & 7;
    int nt = t >> 3;
    int n = nt * 16 + (lane & 15);
    int kbase = kt * 32 + (lane >> 4) * 8;
    ushort_t v[8];
    #pragma unroll
    for (int j = 0; j < 8; ++j) {
        int k = kbase + j;
        float w = (k < 128) ? Wl[k * N + n] : Wr[(k - 128) * N + n];
        v[j] = f2bf(w);
    }
    *(uint4*)(pack + (long)tid * 8) = *(uint4*)v;
}

// ---------------- gather-mean (bf16 in, fp32 acc, bf16 out) ----------------
__global__ void gather_mean_kernel(const int* __restrict__ off, const int* __restrict__ csr_src,
                                   const ushort_t* __restrict__ feat, ushort_t* __restrict__ mean_out) {
    int lane  = threadIdx.x & 15;
    int local = threadIdx.x >> 4;
    long i = (long)blockIdx.x * 16 + local;
    if (i >= N_NODES) return;
    int beg = off[i], end = off[i + 1];
    float acc[8] = {0.f, 0.f, 0.f, 0.f, 0.f, 0.f, 0.f, 0.f};
    for (int k = beg; k < end; ++k) {
        int s = csr_src[k];
        uint4 u = *(const uint4*)(feat + (long)s * 128 + lane * 8);
        acc[0] += __uint_as_float(u.x << 16);
        acc[1] += __uint_as_float(u.x & 0xffff0000u);
        acc[2] += __uint_as_float(u.y << 16);
        acc[3] += __uint_as_float(u.y & 0xffff0000u);
        acc[4] += __uint_as_float(u.z << 16);
        acc[5] += __uint_as_float(u.z & 0xffff0000u);
        acc[6] += __uint_as_float(u.w << 16);
        acc[7] += __uint_as_float(u.w & 0xffff0000u);
    }
    float inv = (end > beg) ? 1.f / (float)(end - beg) : 0.f;
    uint4 o;
    o.x = pack2bf(acc[0] * inv, acc[1] * inv);
    o.y = pack2bf(acc[2] * inv, acc[3] * inv);
    o.z = pack2bf(acc[4] * inv, acc[5] * inv);
    o.w = pack2bf(acc[6] * inv, acc[7] * inv);
    *(uint4*)(mean_out + i * 128 + lane * 8) = o;
}

// ---------------- MFMA MLP: out = relu([mean|x] @ packedW + b) ----------------
template<int NOUT, bool OUT_BF16>
__global__ __launch_bounds__(256) void mfma_mlp_kernel(
        const ushort_t* __restrict__ Am, const ushort_t* __restrict__ Ax,
        const ushort_t* __restrict__ pack, const float* __restrict__ bias,
        void* __restrict__ outv) {
    constexpr int NT = NOUT / 16;
    int lane = threadIdx.x & 63;
    int wave = threadIdx.x >> 6;
    long m0 = (long)blockIdx.x * 64 + wave * 16;
    int r = lane & 15;
    int quad = lane >> 4;
    long arow = m0 + r;
    if (arow > N_NODES - 1) arow = N_NODES - 1;

    bf16x8 areg[8];
    #pragma unroll
    for (int kt = 0; kt < 8; ++kt) {
        const ushort_t* s = (kt < 4) ? Am : Ax;
        int k = (kt & 3) * 32 + quad * 8;
        areg[kt] = *(const bf16x8*)(s + arow * 128 + k);
    }

    f32x4 acc[NT];
    #pragma unroll
    for (int nt = 0; nt < NT; ++nt) acc[nt] = (f32x4){0.f, 0.f, 0.f, 0.f};

    #pragma unroll
    for (int nt = 0; nt < NT; ++nt) {
        #pragma unroll
        for (int kt = 0; kt < 8; ++kt) {
            bf16x8 bfrag = *(const bf16x8*)(pack + ((long)(nt * 8 + kt) * 64 + lane) * 8);
            acc[nt] = __builtin_amdgcn_mfma_f32_16x16x32_bf16(areg[kt], bfrag, acc[nt], 0, 0, 0);
        }
    }

    #pragma unroll
    for (int nt = 0; nt < NT; ++nt) {
        int col = nt * 16 + r;
        float bj = bias[col];
        #pragma unroll
        for (int q = 0; q < 4; ++q) {
            long orow = m0 + quad * 4 + q;
            if (orow < N_NODES) {
                float v = fmaxf(acc[nt][q] + bj, 0.f);
                if (OUT_BF16) ((ushort_t*)outv)[orow * NOUT + col] = f2bf(v);
                else          ((float*)outv)[orow * NOUT + col] = v;
            }
        }
    }
}

extern "C" void kernel_launch(void* const* d_in, const int* in_sizes, int n_in,
                              void* d_out, int out_size, void* d_ws, size_t ws_size,
                              hipStream_t stream) {
    const float* x    = (const float*)d_in[0];
    const int*   ei   = (const int*)d_in[1];
    const float* W1_l = (const float*)d_in[2];
    const float* W1_r = (const float*)d_in[3];
    const float* b1   = (const float*)d_in[4];
    const float* W2_l = (const float*)d_in[5];
    const float* W2_r = (const float*)d_in[6];
    const float* b2   = (const float*)d_in[7];
    float* out = (float*)d_out;

    const int* src = ei;
    const int* dst = ei + N_EDGES;

    // workspace layout (all 16B aligned)
    int* gHist  = (int*)d_ws;                      // 512
    int* bbase  = gHist + 512;                     // 512 (needs NB+1)
    int* gCur   = bbase + 512;                     // 512
    int* off    = gCur + 512;                      // 100352 + pad
    int* bedges = off + 100608;                    // 1.6M
    int* csr    = bedges + N_EDGES;                // 1.6M
    ushort_t* xb    = (ushort_t*)(csr + N_EDGES);  // 25.6 MB
    ushort_t* meanb = xb + (long)N_NODES * 128;    // 25.6 MB
    ushort_t* hb    = meanb + (long)N_NODES * 128; // 25.6 MB
    ushort_t* pack1 = hb + (long)N_NODES * 128;    // 256*128 bf16
    ushort_t* pack2 = pack1 + 256 * 128;           // 256*64 bf16

    // ---- CSR build (bucketed counting sort; no global fine-grained atomics) ----
    hipMemsetAsync(gHist, 0, NB * sizeof(int), stream);
    bucket_hist_kernel<<<PART_BLOCKS, 256, 0, stream>>>(dst, gHist);
    bucket_scan_kernel<<<1, 512, 0, stream>>>(gHist, bbase, gCur);
    bucket_scatter_kernel<<<PART_BLOCKS, 256, 0, stream>>>(src, dst, gCur, bedges);
    bucket_sort_kernel<<<NB, 256, 0, stream>>>(bbase, bedges, csr, off);

    // ---- precision prep ----
    cvt_bf16_kernel<<<((long)N_NODES * 128 / 8 + 255) / 256, 256, 0, stream>>>(
        x, xb, (long)N_NODES * 128);
    pack_w_kernel<<<((128 / 16) * 8 * 64 + 255) / 256, 256, 0, stream>>>(W1_l, W1_r, pack1, 128);
    pack_w_kernel<<<((64 / 16) * 8 * 64 + 255) / 256, 256, 0, stream>>>(W2_l, W2_r, pack2, 64);

    // ---- layer 1 ----
    gather_mean_kernel<<<(N_NODES + 15) / 16, 256, 0, stream>>>(off, csr, xb, meanb);
    mfma_mlp_kernel<128, true><<<(N_NODES + 63) / 64, 256, 0, stream>>>(meanb, xb, pack1, b1, hb);

    // ---- layer 2 ----
    gather_mean_kernel<<<(N_NODES + 15) / 16, 256, 0, stream>>>(off, csr, hb, meanb);
    mfma_mlp_kernel<64, false><<<(N_NODES + 63) / 64, 256, 0, stream>>>(meanb, hb, pack2, b2, out);
}

// Round 6
// 327.150 us; speedup vs baseline: 20.3236x; 1.0943x over previous
//
#include <hip/hip_runtime.h>

#define N_NODES 100000
#define N_EDGES 1600000
#define D_IN 128
#define D_HID 128
#define D_LAT 64

#define BSHIFT 8                          // 256 nodes per bucket
#define NB 392                            // ceil(100352 / 256) buckets
#define CAP 4608                          // slots per bucket region (mean 4082 + 8.2 sigma)
#define EPB 4096                          // edges per partition block
#define PART_BLOCKS ((N_EDGES + EPB - 1) / EPB)   // 391

typedef unsigned short ushort_t;
typedef unsigned int uint_t;
using bf16x8 = __attribute__((ext_vector_type(8))) short;
using f32x4  = __attribute__((ext_vector_type(4))) float;

__device__ inline ushort_t f2bf(float f) {
    uint_t u = __float_as_uint(f);
    return (ushort_t)((u + 0x7fffu + ((u >> 16) & 1u)) >> 16);   // RNE
}
__device__ inline uint_t pack2bf(float a, float b) {
    return (uint_t)f2bf(a) | ((uint_t)f2bf(b) << 16);
}
__device__ inline float bf2f(ushort_t u) {
    return __uint_as_float(((uint_t)u) << 16);
}

// ---------------- CSR build: fixed-stride bucketed counting sort ----------------
__global__ void init_cursor_kernel(int* __restrict__ gCur) {
    int t = blockIdx.x * blockDim.x + threadIdx.x;
    if (t < NB) gCur[t] = t * CAP;
}

// partition edges into fixed-stride bucket regions, packed (dstLocal<<24)|src
__global__ __launch_bounds__(256) void bucket_scatter_kernel(const int* __restrict__ src,
                                                             const int* __restrict__ dst,
                                                             int* __restrict__ gCur,
                                                             int* __restrict__ bedges) {
    __shared__ int h[NB];
    __shared__ int start[NB];
    for (int j = threadIdx.x; j < NB; j += 256) h[j] = 0;
    __syncthreads();
    long base = (long)blockIdx.x * EPB;
    #pragma unroll
    for (int i = 0; i < EPB / 256; ++i) {
        long e = base + i * 256 + threadIdx.x;
        if (e < N_EDGES) atomicAdd(&h[dst[e] >> BSHIFT], 1);
    }
    __syncthreads();
    for (int j = threadIdx.x; j < NB; j += 256)
        start[j] = h[j] ? atomicAdd(&gCur[j], h[j]) : 0;
    __syncthreads();
    #pragma unroll
    for (int i = 0; i < EPB / 256; ++i) {
        long e = base + i * 256 + threadIdx.x;
        if (e < N_EDGES) {
            int d = dst[e];
            int b = d >> BSHIFT;
            int p = atomicAdd(&start[b], 1);
            if (p < (b + 1) * CAP)                     // overflow clamp (P ~ 1e-16)
                bedges[p] = ((d & 255) << 24) | src[e];
        }
    }
}

// per-bucket LDS counting sort -> csr region + per-node (beg,deg)
__global__ __launch_bounds__(256) void bucket_sort_kernel(const int* __restrict__ gCur,
                                                          const int* __restrict__ bedges,
                                                          int* __restrict__ csr,
                                                          int2* __restrict__ off2) {
    __shared__ int sdata[256];
    __shared__ int cur[256];
    int b = blockIdx.x, t = threadIdx.x;
    int r0 = b * CAP;
    int n = gCur[b] - r0;
    if (n > CAP) n = CAP;
    cur[t] = 0;
    __syncthreads();
    for (int k = t; k < n; k += 256) atomicAdd(&cur[(unsigned)bedges[r0 + k] >> 24], 1);
    __syncthreads();
    int c = cur[t];
    sdata[t] = c;
    __syncthreads();
    for (int d = 1; d < 256; d <<= 1) {
        int u = (t >= d) ? sdata[t - d] : 0;
        __syncthreads();
        sdata[t] += u;
        __syncthreads();
    }
    int ex = (t == 0) ? 0 : sdata[t - 1];
    off2[(b << BSHIFT) + t] = make_int2(r0 + ex, c);
    cur[t] = ex;
    __syncthreads();
    for (int k = t; k < n; k += 256) {
        int v = bedges[r0 + k];
        int p = atomicAdd(&cur[(unsigned)v >> 24], 1);
        csr[r0 + p] = v & 0xFFFFFF;
    }
}

// ---------------- fp32 -> bf16 conversion (8 elems/thread) ----------------
__global__ void cvt_bf16_kernel(const float* __restrict__ in, ushort_t* __restrict__ out, long n) {
    long i = ((long)blockIdx.x * blockDim.x + threadIdx.x) * 8;
    if (i >= n) return;
    float4 a = *(const float4*)(in + i);
    float4 b = *(const float4*)(in + i + 4);
    uint4 o;
    o.x = pack2bf(a.x, a.y);
    o.y = pack2bf(a.z, a.w);
    o.z = pack2bf(b.x, b.y);
    o.w = pack2bf(b.z, b.w);
    *(uint4*)(out + i) = o;
}

// ---------------- pack [Wl;Wr] (K=256 x N) into MFMA B-fragment order ----------------
// dest: [N/16][8][64 lanes][8 bf16]; lane holds B[k=kt*32+quad*8+j][n=nt*16+(lane&15)]
__global__ void pack_w_kernel(const float* __restrict__ Wl, const float* __restrict__ Wr,
                              ushort_t* __restrict__ pack, int N) {
    int tid = blockIdx.x * blockDim.x + threadIdx.x;
    int total = (N / 16) * 8 * 64;
    if (tid >= total) return;
    int lane = tid & 63;
    int t = tid >> 6;
    int kt = t & 7;
    int nt = t >> 3;
    int n = nt * 16 + (lane & 15);
    int kbase = kt * 32 + (lane >> 4) * 8;
    ushort_t v[8];
    #pragma unroll
    for (int j = 0; j < 8; ++j) {
        int k = kbase + j;
        float w = (k < 128) ? Wl[k * N + n] : Wr[(k - 128) * N + n];
        v[j] = f2bf(w);
    }
    *(uint4*)(pack + (long)tid * 8) = *(uint4*)v;
}

// single-matrix pack, K=128: dest [N/16][4][64][8]
__global__ void pack_wk128_kernel(const float* __restrict__ W, ushort_t* __restrict__ pack, int N) {
    int tid = blockIdx.x * blockDim.x + threadIdx.x;
    int total = (N / 16) * 4 * 64;
    if (tid >= total) return;
    int lane = tid & 63;
    int t = tid >> 6;
    int kt = t & 3;
    int nt = t >> 2;
    int n = nt * 16 + (lane & 15);
    int kbase = kt * 32 + (lane >> 4) * 8;
    ushort_t v[8];
    #pragma unroll
    for (int j = 0; j < 8; ++j) v[j] = f2bf(W[(kbase + j) * N + n]);
    *(uint4*)(pack + (long)tid * 8) = *(uint4*)v;
}

// ---------------- gather-mean 128-dim (bf16 in, fp32 acc, bf16 out) ----------------
__global__ void gather_mean_kernel(const int2* __restrict__ off2, const int* __restrict__ csr_src,
                                   const ushort_t* __restrict__ feat, ushort_t* __restrict__ mean_out) {
    int lane  = threadIdx.x & 15;
    int local = threadIdx.x >> 4;
    long i = (long)blockIdx.x * 16 + local;
    if (i >= N_NODES) return;
    int2 bd = off2[i];
    int beg = bd.x, n = bd.y;
    float acc[8] = {0.f, 0.f, 0.f, 0.f, 0.f, 0.f, 0.f, 0.f};
    for (int k = 0; k < n; ++k) {
        int s = csr_src[beg + k];
        uint4 u = *(const uint4*)(feat + (long)s * 128 + lane * 8);
        acc[0] += __uint_as_float(u.x << 16);
        acc[1] += __uint_as_float(u.x & 0xffff0000u);
        acc[2] += __uint_as_float(u.y << 16);
        acc[3] += __uint_as_float(u.y & 0xffff0000u);
        acc[4] += __uint_as_float(u.z << 16);
        acc[5] += __uint_as_float(u.z & 0xffff0000u);
        acc[6] += __uint_as_float(u.w << 16);
        acc[7] += __uint_as_float(u.w & 0xffff0000u);
    }
    float inv = (n > 0) ? 1.f / (float)n : 0.f;
    uint4 o;
    o.x = pack2bf(acc[0] * inv, acc[1] * inv);
    o.y = pack2bf(acc[2] * inv, acc[3] * inv);
    o.z = pack2bf(acc[4] * inv, acc[5] * inv);
    o.w = pack2bf(acc[6] * inv, acc[7] * inv);
    *(uint4*)(mean_out + i * 128 + lane * 8) = o;
}

// ---------------- gather-mean 64-dim ----------------
__global__ void gather_mean64_kernel(const int2* __restrict__ off2, const int* __restrict__ csr_src,
                                     const ushort_t* __restrict__ feat, ushort_t* __restrict__ mean_out) {
    int lane  = threadIdx.x & 7;
    int local = threadIdx.x >> 3;
    long i = (long)blockIdx.x * 32 + local;
    if (i >= N_NODES) return;
    int2 bd = off2[i];
    int beg = bd.x, n = bd.y;
    float acc[8] = {0.f, 0.f, 0.f, 0.f, 0.f, 0.f, 0.f, 0.f};
    for (int k = 0; k < n; ++k) {
        int s = csr_src[beg + k];
        uint4 u = *(const uint4*)(feat + (long)s * 64 + lane * 8);
        acc[0] += __uint_as_float(u.x << 16);
        acc[1] += __uint_as_float(u.x & 0xffff0000u);
        acc[2] += __uint_as_float(u.y << 16);
        acc[3] += __uint_as_float(u.y & 0xffff0000u);
        acc[4] += __uint_as_float(u.z << 16);
        acc[5] += __uint_as_float(u.z & 0xffff0000u);
        acc[6] += __uint_as_float(u.w << 16);
        acc[7] += __uint_as_float(u.w & 0xffff0000u);
    }
    float inv = (n > 0) ? 1.f / (float)n : 0.f;
    uint4 o;
    o.x = pack2bf(acc[0] * inv, acc[1] * inv);
    o.y = pack2bf(acc[2] * inv, acc[3] * inv);
    o.z = pack2bf(acc[4] * inv, acc[5] * inv);
    o.w = pack2bf(acc[6] * inv, acc[7] * inv);
    *(uint4*)(mean_out + i * 64 + lane * 8) = o;
}

// ---------------- MFMA MLP (K=256): out = relu([Am|Ax] @ packedW + b) ----------------
template<int NOUT, bool OUT_BF16>
__global__ __launch_bounds__(256) void mfma_mlp_kernel(
        const ushort_t* __restrict__ Am, const ushort_t* __restrict__ Ax,
        const ushort_t* __restrict__ pack, const float* __restrict__ bias,
        void* __restrict__ outv) {
    constexpr int NT = NOUT / 16;
    int lane = threadIdx.x & 63;
    int wave = threadIdx.x >> 6;
    long m0 = (long)blockIdx.x * 64 + wave * 16;
    int r = lane & 15;
    int quad = lane >> 4;
    long arow = m0 + r;
    if (arow > N_NODES - 1) arow = N_NODES - 1;

    bf16x8 areg[8];
    #pragma unroll
    for (int kt = 0; kt < 8; ++kt) {
        const ushort_t* s = (kt < 4) ? Am : Ax;
        int k = (kt & 3) * 32 + quad * 8;
        areg[kt] = *(const bf16x8*)(s + arow * 128 + k);
    }

    f32x4 acc[NT];
    #pragma unroll
    for (int nt = 0; nt < NT; ++nt) acc[nt] = (f32x4){0.f, 0.f, 0.f, 0.f};

    #pragma unroll
    for (int nt = 0; nt < NT; ++nt) {
        #pragma unroll
        for (int kt = 0; kt < 8; ++kt) {
            bf16x8 bfrag = *(const bf16x8*)(pack + ((long)(nt * 8 + kt) * 64 + lane) * 8);
            acc[nt] = __builtin_amdgcn_mfma_f32_16x16x32_bf16(areg[kt], bfrag, acc[nt], 0, 0, 0);
        }
    }

    #pragma unroll
    for (int nt = 0; nt < NT; ++nt) {
        int col = nt * 16 + r;
        float bj = bias[col];
        #pragma unroll
        for (int q = 0; q < 4; ++q) {
            long orow = m0 + quad * 4 + q;
            if (orow < N_NODES) {
                float v = fmaxf(acc[nt][q] + bj, 0.f);
                if (OUT_BF16) ((ushort_t*)outv)[orow * NOUT + col] = f2bf(v);
                else          ((float*)outv)[orow * NOUT + col] = v;
            }
        }
    }
}

// ---------------- MFMA GEMM (K=128): out = [relu]( A @ packedW [+ Cpre] [+ b] ) ----------------
template<int NOUT, bool OUT_BF16, bool PRELOAD, bool HASBIAS, bool RELU>
__global__ __launch_bounds__(256) void mfma_gemm_k128_kernel(
        const ushort_t* __restrict__ A, const ushort_t* __restrict__ pack,
        const float* __restrict__ bias, const ushort_t* __restrict__ Cpre,
        void* __restrict__ outv) {
    constexpr int NT = NOUT / 16;
    int lane = threadIdx.x & 63;
    int wave = threadIdx.x >> 6;
    long m0 = (long)blockIdx.x * 64 + wave * 16;
    int r = lane & 15;
    int quad = lane >> 4;
    long arow = m0 + r;
    if (arow > N_NODES - 1) arow = N_NODES - 1;

    bf16x8 areg[4];
    #pragma unroll
    for (int kt = 0; kt < 4; ++kt)
        areg[kt] = *(const bf16x8*)(A + arow * 128 + kt * 32 + quad * 8);

    f32x4 acc[NT];
    #pragma unroll
    for (int nt = 0; nt < NT; ++nt) {
        if (PRELOAD) {
            int col = nt * 16 + r;
            #pragma unroll
            for (int q = 0; q < 4; ++q) {
                long row = m0 + quad * 4 + q;
                if (row > N_NODES - 1) row = N_NODES - 1;
                acc[nt][q] = bf2f(Cpre[row * NOUT + col]);
            }
        } else {
            acc[nt] = (f32x4){0.f, 0.f, 0.f, 0.f};
        }
    }

    #pragma unroll
    for (int nt = 0; nt < NT; ++nt) {
        #pragma unroll
        for (int kt = 0; kt < 4; ++kt) {
            bf16x8 bfrag = *(const bf16x8*)(pack + ((long)(nt * 4 + kt) * 64 + lane) * 8);
            acc[nt] = __builtin_amdgcn_mfma_f32_16x16x32_bf16(areg[kt], bfrag, acc[nt], 0, 0, 0);
        }
    }

    #pragma unroll
    for (int nt = 0; nt < NT; ++nt) {
        int col = nt * 16 + r;
        float bj = HASBIAS ? bias[col] : 0.f;
        #pragma unroll
        for (int q = 0; q < 4; ++q) {
            long orow = m0 + quad * 4 + q;
            if (orow < N_NODES) {
                float v = acc[nt][q] + bj;
                if (RELU) v = fmaxf(v, 0.f);
                if (OUT_BF16) ((ushort_t*)outv)[orow * NOUT + col] = f2bf(v);
                else          ((float*)outv)[orow * NOUT + col] = v;
            }
        }
    }
}

extern "C" void kernel_launch(void* const* d_in, const int* in_sizes, int n_in,
                              void* d_out, int out_size, void* d_ws, size_t ws_size,
                              hipStream_t stream) {
    const float* x    = (const float*)d_in[0];
    const int*   ei   = (const int*)d_in[1];
    const float* W1_l = (const float*)d_in[2];
    const float* W1_r = (const float*)d_in[3];
    const float* b1   = (const float*)d_in[4];
    const float* W2_l = (const float*)d_in[5];
    const float* W2_r = (const float*)d_in[6];
    const float* b2   = (const float*)d_in[7];
    float* out = (float*)d_out;

    const int* src = ei;
    const int* dst = ei + N_EDGES;

    // workspace layout (16B aligned). g/meang alias mean1's 25.6 MB region.
    int*  gCur   = (int*)d_ws;                        // 512
    int2* off2   = (int2*)(gCur + 512);               // 100608 int2
    int*  bedges = (int*)(off2 + 100608);             // NB*CAP
    int*  csr    = bedges + NB * CAP;                 // NB*CAP
    ushort_t* xb    = (ushort_t*)(csr + NB * CAP);    // 25.6 MB
    ushort_t* mean1 = xb + (long)N_NODES * 128;       // 25.6 MB region
    ushort_t* g     = mean1;                          // alias (12.8 MB, used after mean1 dead)
    ushort_t* meang = mean1 + (long)N_NODES * 64;     // alias upper half (12.8 MB)
    ushort_t* hb    = mean1 + (long)N_NODES * 128;    // 25.6 MB
    ushort_t* pack1  = hb + (long)N_NODES * 128;      // 256*128 bf16
    ushort_t* pack2l = pack1 + 256 * 128;             // 128*64
    ushort_t* pack2r = pack2l + 128 * 64;             // 128*64

    // ---- CSR build (fixed-stride buckets; no hist/scan passes) ----
    init_cursor_kernel<<<2, 256, 0, stream>>>(gCur);
    bucket_scatter_kernel<<<PART_BLOCKS, 256, 0, stream>>>(src, dst, gCur, bedges);
    bucket_sort_kernel<<<NB, 256, 0, stream>>>(gCur, bedges, csr, off2);

    // ---- precision prep ----
    cvt_bf16_kernel<<<((long)N_NODES * 128 / 8 + 255) / 256, 256, 0, stream>>>(
        x, xb, (long)N_NODES * 128);
    pack_w_kernel<<<((128 / 16) * 8 * 64 + 255) / 256, 256, 0, stream>>>(W1_l, W1_r, pack1, 128);
    pack_wk128_kernel<<<((64 / 16) * 4 * 64 + 255) / 256, 256, 0, stream>>>(W2_l, pack2l, 64);
    pack_wk128_kernel<<<((64 / 16) * 4 * 64 + 255) / 256, 256, 0, stream>>>(W2_r, pack2r, 64);

    // ---- layer 1: mean1 = gather(x); h = relu([mean1|x]@W1 + b1) ----
    gather_mean_kernel<<<(N_NODES + 15) / 16, 256, 0, stream>>>(off2, csr, xb, mean1);
    mfma_mlp_kernel<128, true><<<(N_NODES + 63) / 64, 256, 0, stream>>>(mean1, xb, pack1, b1, hb);

    // ---- layer 2 (pre-transformed): g = h@W2_l; meang = gather(g);
    //      out = relu(meang + h@W2_r + b2) ----
    mfma_gemm_k128_kernel<64, true, false, false, false><<<(N_NODES + 63) / 64, 256, 0, stream>>>(
        hb, pack2l, nullptr, nullptr, g);
    gather_mean64_kernel<<<(N_NODES + 31) / 32, 256, 0, stream>>>(off2, csr, g, meang);
    mfma_gemm_k128_kernel<64, false, true, true, true><<<(N_NODES + 63) / 64, 256, 0, stream>>>(
        hb, pack2r, b2, meang, out);
}